// Round 14
// baseline (213.721 us; speedup 1.0000x reference)
//
#include <hip/hip_runtime.h>
#include <math.h>

#define BB   4
#define SS   4096
#define DD   1024
#define BL   128
#define NB   32

typedef __attribute__((ext_vector_type(4))) float f32x4;
typedef __attribute__((ext_vector_type(16))) float f32x16;
typedef __attribute__((ext_vector_type(8))) short bf16x8;
typedef __attribute__((ext_vector_type(8))) unsigned short u16x8;

__device__ __forceinline__ float bf2f(unsigned short u) {
    return __uint_as_float(((unsigned int)u) << 16);
}
__device__ __forceinline__ unsigned short f2bf(float f) {
    unsigned int u = __float_as_uint(f);
    return (unsigned short)((u + 0x7FFFu + ((u >> 16) & 1u)) >> 16);  // RNE
}
__device__ __forceinline__ void gload_lds16(const unsigned short* g, unsigned short* l) {
    __builtin_amdgcn_global_load_lds(
        (const __attribute__((address_space(1))) void*)g,
        (__attribute__((address_space(3))) void*)l, 16, 0, 0);
}

// ---------------- fp32 -> bf16 elementwise ----------------
__global__ __launch_bounds__(256) void cvt_f32_bf16(const float4* __restrict__ in,
                                                    ushort4* __restrict__ out, int n4) {
    int i = blockIdx.x * 256 + threadIdx.x;
    if (i < n4) {
        float4 v = in[i];
        ushort4 o;
        o.x = f2bf(v.x); o.y = f2bf(v.y); o.z = f2bf(v.z); o.w = f2bf(v.w);
        out[i] = o;
    }
}

// ---------------- transpose + convert: W[K][N] f32 -> WT[N][K] bf16 ----------------
__global__ __launch_bounds__(256) void transcvt(const float* __restrict__ W,
                                                unsigned short* __restrict__ WT,
                                                int K, int N) {
    __shared__ float tile[32][33];
    const int n0 = blockIdx.x * 32, k0 = blockIdx.y * 32;
    const int tx = threadIdx.x & 31, ty = threadIdx.x >> 5;  // ty 0..7
    #pragma unroll
    for (int r = 0; r < 32; r += 8)
        tile[ty + r][tx] = W[(size_t)(k0 + ty + r) * N + n0 + tx];
    __syncthreads();
    #pragma unroll
    for (int r = 0; r < 32; r += 8)
        WT[(size_t)(n0 + ty + r) * K + k0 + tx] = f2bf(tile[tx][ty + r]);
}

// ---------------- 256x256 bf16 MFMA GEMM, 4-phase, NO sched_barrier ----------------
// A: [M][K] bf16 row-major; BT: [N][K] bf16; C: [M][N] OutT.
// BK=64, 512 threads = 8 waves (2M x 4N). Per wave: 128x64 out = 8x4 16x16 frags.
// LDS: 2 dbuf x (256x64) A + B in one 128 KiB arena, XOR-swizzled in 16B chunks.
//
// r3-r12 lesson: five schedule variants (8-phase, lgkm-ahead, 2-phase...) all pin at
// 113-116 us; every one wrapped its waitcnts in sched_barrier(0) (4-8 hard scheduler
// fences per K-tile). The m201 template uses BARE s_waitcnt (compiler free to
// interleave VALU/addr-calc into the MFMA cluster); rule-18's sched_barrier is only
// needed for inline-asm ds_reads — ours are C++ derefs with compiler-tracked deps.
// This round removes ALL sched_barriers (single active variable) + adds the
// template's lgkmcnt(8) pacing hint in the 12-read phase.
// REGISTER BUDGET: 8 waves => 2 waves/SIMD => hard 256 regs/wave; acc=128 AGPR,
// B(32)+A(16)+addressing < 128 arch VGPRs (r8 spill lesson; canary: WRITE_SIZE).

#define GBAR() __builtin_amdgcn_s_barrier()
#define WAIT_LGKM0() asm volatile("s_waitcnt lgkmcnt(0)" ::: "memory")
#define WAIT_LGKM8() asm volatile("s_waitcnt lgkmcnt(8)" ::: "memory")

#define MFMA_PAIR2(q, ni) \
    acc[(q)*2+0][ni] = __builtin_amdgcn_mfma_f32_16x16x32_bf16(aC[0][0], bC[ni][0], acc[(q)*2+0][ni], 0, 0, 0); \
    acc[(q)*2+0][ni] = __builtin_amdgcn_mfma_f32_16x16x32_bf16(aC[0][1], bC[ni][1], acc[(q)*2+0][ni], 0, 0, 0); \
    acc[(q)*2+1][ni] = __builtin_amdgcn_mfma_f32_16x16x32_bf16(aC[1][0], bC[ni][0], acc[(q)*2+1][ni], 0, 0, 0); \
    acc[(q)*2+1][ni] = __builtin_amdgcn_mfma_f32_16x16x32_bf16(aC[1][1], bC[ni][1], acc[(q)*2+1][ni], 0, 0, 0);

#define MFMA_Q(q) do { \
    __builtin_amdgcn_s_setprio(1); \
    MFMA_PAIR2(q, 0) MFMA_PAIR2(q, 1) MFMA_PAIR2(q, 2) MFMA_PAIR2(q, 3) \
    __builtin_amdgcn_s_setprio(0); } while (0)

#define READ_AQ(pA_, q) do { \
    aC[0][0] = *(const bf16x8*)((pA_) + ((q)*2+0)*1024 + sw0); \
    aC[0][1] = *(const bf16x8*)((pA_) + ((q)*2+0)*1024 + sw1); \
    aC[1][0] = *(const bf16x8*)((pA_) + ((q)*2+1)*1024 + sw0); \
    aC[1][1] = *(const bf16x8*)((pA_) + ((q)*2+1)*1024 + sw1); } while (0)

#define READ_B8(pB_) do { \
    bC[0][0] = *(const bf16x8*)((pB_) + 0*1024 + sw0); \
    bC[0][1] = *(const bf16x8*)((pB_) + 0*1024 + sw1); \
    bC[1][0] = *(const bf16x8*)((pB_) + 1*1024 + sw0); \
    bC[1][1] = *(const bf16x8*)((pB_) + 1*1024 + sw1); \
    bC[2][0] = *(const bf16x8*)((pB_) + 2*1024 + sw0); \
    bC[2][1] = *(const bf16x8*)((pB_) + 2*1024 + sw1); \
    bC[3][0] = *(const bf16x8*)((pB_) + 3*1024 + sw0); \
    bC[3][1] = *(const bf16x8*)((pB_) + 3*1024 + sw1); } while (0)

template<typename OutT>
__global__ __launch_bounds__(512, 1) void gemm256(
    const unsigned short* __restrict__ A, const unsigned short* __restrict__ BT,
    const float* __restrict__ bias, OutT* __restrict__ C,
    int M, int N, int K, int ntn)
{
    __shared__ __align__(16) unsigned short smem[65536];   // 128 KiB arena
    unsigned short* sAb = smem;
    unsigned short* sBb = smem + 32768;

    const int nwg = gridDim.x;
    const int wg  = blockIdx.x;
    const int swzb = (wg & 7) * (nwg >> 3) + (wg >> 3);   // bijective: nwg % 8 == 0
    const int m0 = (swzb / ntn) * 256, n0 = (swzb % ntn) * 256;

    const int t    = threadIdx.x;
    const int w    = t >> 6;
    const int lane = t & 63;
    const int wm   = w >> 2, wn = w & 3;

    const int srow8 = lane >> 3;
    const int sgch  = (lane & 7) ^ srow8;     // pre-swizzled global k-chunk
    const int NT    = K >> 6;                 // K-tiles of 64 (>= 2 for all launches)

    auto STAGE_A = [&](int ts, int cb) {
        const int r = cb + (w << 3);
        gload_lds16(A + (size_t)(m0 + r + srow8) * K + (ts << 6) + sgch * 8,
                    sAb + (size_t)(ts & 1) * 16384 + r * 64);
    };
    auto STAGE_B = [&](int ts, int cb) {
        const int r = cb + (w << 3);
        gload_lds16(BT + (size_t)(n0 + r + srow8) * K + (ts << 6) + sgch * 8,
                    sBb + (size_t)(ts & 1) * 16384 + r * 64);
    };

    const int frA = wm * 128 + (lane & 15);
    const int frB = wn * 64  + (lane & 15);
    const int sw0 = (((lane >> 4) + 0) ^ (lane & 7)) * 8;
    const int sw1 = (((lane >> 4) + 4) ^ (lane & 7)) * 8;

    f32x4 acc[8][4];
    #pragma unroll
    for (int i = 0; i < 8; ++i)
        #pragma unroll
        for (int j = 0; j < 4; ++j) acc[i][j] = (f32x4){0.f, 0.f, 0.f, 0.f};

    bf16x8 bC[4][2];    // B-regs for current tile (32 VGPRs)
    bf16x8 aC[2][2];    // A-quarter regs, reused each phase (16 VGPRs)

    // ---- prologue: tile0 full; B(1) full + A(1){0,128} stay in flight ----
    STAGE_B(0, 0); STAGE_B(0, 64); STAGE_B(0, 128); STAGE_B(0, 192);
    STAGE_A(0, 0); STAGE_A(0, 64); STAGE_A(0, 128); STAGE_A(0, 192);
    asm volatile("s_waitcnt vmcnt(4)" ::: "memory");
    if (NT > 1) {
        STAGE_B(1, 0); STAGE_B(1, 64); STAGE_B(1, 128); STAGE_B(1, 192);
        STAGE_A(1, 0); STAGE_A(1, 128);
        asm volatile("s_waitcnt vmcnt(6)" ::: "memory");
    } else {
        asm volatile("s_waitcnt vmcnt(0)" ::: "memory");
    }
    GBAR();

    for (int ts = 0; ts < NT; ++ts) {
        const unsigned short* pAc = sAb + (size_t)(ts & 1) * 16384 + frA * 64;
        const unsigned short* pBc = sBb + (size_t)(ts & 1) * 16384 + frB * 64;

        // ---- P1: read B8 + A-q0 (12 reads); stage A(ts+1){64,192}; lgkm(8) pace ----
        READ_B8(pBc);
        READ_AQ(pAc, 0);
        if (ts + 1 < NT) { STAGE_A(ts + 1, 64); STAGE_A(ts + 1, 192); }
        WAIT_LGKM8();
        GBAR(); WAIT_LGKM0(); MFMA_Q(0); GBAR();

        // ---- P2: read A-q1; stage B(ts+2)-lo ----
        READ_AQ(pAc, 1);
        if (ts + 2 < NT) { STAGE_B(ts + 2, 0); STAGE_B(ts + 2, 64); }
        GBAR(); WAIT_LGKM0(); MFMA_Q(1); GBAR();

        // ---- P3: read A-q2; stage B(ts+2)-hi ----
        READ_AQ(pAc, 2);
        if (ts + 2 < NT) { STAGE_B(ts + 2, 128); STAGE_B(ts + 2, 192); }
        GBAR(); WAIT_LGKM0(); MFMA_Q(2); GBAR();

        // ---- P4: read A-q3; stage A(ts+2){0,128}; counted vmcnt ----
        READ_AQ(pAc, 3);
        if (ts + 2 < NT) { STAGE_A(ts + 2, 0); STAGE_A(ts + 2, 128); }
        GBAR(); WAIT_LGKM0(); MFMA_Q(3);
        if (ts + 2 < NT) { asm volatile("s_waitcnt vmcnt(6)" ::: "memory"); }
        else             { asm volatile("s_waitcnt vmcnt(0)" ::: "memory"); }
        GBAR();
    }

    // ---- epilogue: LDS-bounce for coalesced wide stores ----
    if constexpr (sizeof(OutT) == 2) {
        unsigned short (*cb)[256] = (unsigned short (*)[256])smem;
        #pragma unroll
        for (int ni = 0; ni < 4; ++ni) {
            const int col = wn * 64 + ni * 16 + (lane & 15);
            const float bv = bias[n0 + col];
            #pragma unroll
            for (int mi = 0; mi < 8; ++mi) {
                const int rb = wm * 128 + mi * 16 + ((lane >> 4) << 2);
                #pragma unroll
                for (int r = 0; r < 4; ++r)
                    cb[rb + r][col] = f2bf(acc[mi][ni][r] + bv);
            }
        }
        __syncthreads();
        unsigned short* Cp = (unsigned short*)C;
        #pragma unroll
        for (int it = 0; it < 16; ++it) {
            const int row = it * 16 + (t >> 5);
            const int cs  = (t & 31) * 8;
            u16x8 v = *(const u16x8*)&cb[row][cs];
            *(u16x8*)(Cp + (size_t)(m0 + row) * N + n0 + cs) = v;
        }
    } else {
        float (*cf)[256] = (float (*)[256])smem;
        #pragma unroll
        for (int h = 0; h < 2; ++h) {
            if (wm == h) {
                #pragma unroll
                for (int ni = 0; ni < 4; ++ni) {
                    const int col = wn * 64 + ni * 16 + (lane & 15);
                    const float bv = bias[n0 + col];
                    #pragma unroll
                    for (int mi = 0; mi < 8; ++mi) {
                        const int rb = mi * 16 + ((lane >> 4) << 2);  // 0..127
                        #pragma unroll
                        for (int r = 0; r < 4; ++r)
                            cf[rb + r][col] = acc[mi][ni][r] + bv;
                    }
                }
            }
            __syncthreads();
            float* Cp = (float*)C;
            #pragma unroll
            for (int it = 0; it < 16; ++it) {
                const int row = it * 8 + (t >> 6);     // 0..127
                const int c4  = (t & 63) * 4;
                float4 v = *(const float4*)&cf[row][c4];
                *(float4*)(Cp + (size_t)(m0 + h * 128 + row) * N + n0 + c4) = v;
            }
            __syncthreads();
        }
    }
}

// ---------------- column attention v3: 8-wave k-split, 4 blocks/CU (r13, frozen) ----------------
__global__ __launch_bounds__(512) void col_attn_mfma(const unsigned short* __restrict__ qkv,
                                                     unsigned short* __restrict__ outb)
{
    const int b  = blockIdx.x >> 7;
    const int bl = blockIdx.x & (BL - 1);

    __shared__ float red[8][32][33];     // 33 KiB
    __shared__ float p_s[NB][NB + 1];

    const int t    = threadIdx.x;
    const int w    = t >> 6;
    const int lane = t & 63;

    const size_t rowstride = (size_t)BL * 3 * DD;
    const unsigned short* base = qkv + ((size_t)b * NB * BL + bl) * (3 * DD);

    // ---- QK^T: wave w covers k in [w*128, w*128+128), 8 MFMA steps ----
    {
        const int arow = lane & 31;
        const int khi  = (lane >> 5) * 8;
        const unsigned short* qp = base + (size_t)arow * rowstride + w * 128 + khi;
        const unsigned short* kp = qp + DD;

        f32x16 acc0 = {}, acc1 = {};
        #pragma unroll
        for (int s = 0; s < 8; s += 2) {
            bf16x8 aq0 = *(const bf16x8*)(qp + s * 16);
            bf16x8 bk0 = *(const bf16x8*)(kp + s * 16);
            bf16x8 aq1 = *(const bf16x8*)(qp + s * 16 + 16);
            bf16x8 bk1 = *(const bf16x8*)(kp + s * 16 + 16);
            acc0 = __builtin_amdgcn_mfma_f32_32x32x16_bf16(aq0, bk0, acc0, 0, 0, 0);
            acc1 = __builtin_amdgcn_mfma_f32_32x32x16_bf16(aq1, bk1, acc1, 0, 0, 0);
        }
        const int ccol = lane & 31;
        const int rhi  = (lane >> 5) * 4;
        #pragma unroll
        for (int r = 0; r < 16; ++r) {
            const int crow = (r & 3) + 8 * (r >> 2) + rhi;
            red[w][crow][ccol] = acc0[r] + acc1[r];
        }
    }
    __syncthreads();

    // ---- reduce 8 waves -> p_s, apply scale (512 threads: row=t>>4, 2 cols each) ----
    {
        const float scale = 1.0f / 32.0f;   // 1/sqrt(1024)
        const int row = t >> 4;
        const int c0  = (t & 15) * 2;
        #pragma unroll
        for (int j = 0; j < 2; ++j) {
            const int c = c0 + j;
            float s = red[0][row][c];
            #pragma unroll
            for (int ww = 1; ww < 8; ++ww) s += red[ww][row][c];
            p_s[row][c] = s * scale;
        }
    }
    __syncthreads();

    // ---- causal softmax (rows on lanes 0..31; tiny) ----
    if (t < NB) {
        const int i = t;
        float mx = p_s[i][0];
        for (int j = 1; j <= i; ++j) mx = fmaxf(mx, p_s[i][j]);
        float sum = 0.f;
        for (int j = 0; j <= i; ++j) { float e = __expf(p_s[i][j] - mx); p_s[i][j] = e; sum += e; }
        const float inv = 1.0f / sum;
        for (int j = 0; j <= i; ++j) p_s[i][j] *= inv;
        for (int j = i + 1; j < NB; ++j) p_s[i][j] = 0.f;
    }
    __syncthreads();

    // ---- PV: two 256-thread groups, balanced pass pairs {0,3} / {1,2} ----
    const int grp = t >> 8;              // 0 or 1
    const int tt  = t & 255;
    const int d0v = tt * 4;
    const unsigned short* vbase = base + 2 * DD;
    const int passes[2][2] = {{0, 3}, {1, 2}};
    #pragma unroll
    for (int pi = 0; pi < 2; ++pi) {
        const int p = passes[grp][pi];
        float4 accv[8];
        #pragma unroll
        for (int ii = 0; ii < 8; ++ii) accv[ii] = make_float4(0.f, 0.f, 0.f, 0.f);
        const int jmax = (p + 1) * 8;
        for (int j = 0; j < jmax; ++j) {
            ushort4 v4 = *(const ushort4*)(vbase + (size_t)j * rowstride + d0v);
            const float vx = bf2f(v4.x), vy = bf2f(v4.y), vz = bf2f(v4.z), vw = bf2f(v4.w);
            #pragma unroll
            for (int ii = 0; ii < 8; ++ii) {
                const float pij = p_s[p * 8 + ii][j];
                accv[ii].x += pij * vx;
                accv[ii].y += pij * vy;
                accv[ii].z += pij * vz;
                accv[ii].w += pij * vw;
            }
        }
        #pragma unroll
        for (int ii = 0; ii < 8; ++ii) {
            const int i = p * 8 + ii;
            ushort4 o;
            o.x = f2bf(accv[ii].x); o.y = f2bf(accv[ii].y);
            o.z = f2bf(accv[ii].z); o.w = f2bf(accv[ii].w);
            *(ushort4*)(outb + ((size_t)(b * NB + i) * BL + bl) * DD + d0v) = o;
        }
    }
}

extern "C" void kernel_launch(void* const* d_in, const int* in_sizes, int n_in,
                              void* d_out, int out_size, void* d_ws, size_t ws_size,
                              hipStream_t stream) {
    (void)in_sizes; (void)n_in; (void)out_size; (void)ws_size;
    const float* x    = (const float*)d_in[0];
    const float* Wqkv = (const float*)d_in[1];
    const float* bqkv = (const float*)d_in[2];
    const float* Wout = (const float*)d_in[3];
    const float* bout = (const float*)d_in[4];
    float* out = (float*)d_out;

    char* ws = (char*)d_ws;
    unsigned short* xb    = (unsigned short*)ws;                        // 32 MiB
    unsigned short* WqkvT = (unsigned short*)(ws + ((size_t)32 << 20)); //  6 MiB
    unsigned short* WoutT = (unsigned short*)(ws + ((size_t)38 << 20)); //  2 MiB
    unsigned short* qkvb  = (unsigned short*)(ws + ((size_t)40 << 20)); // 96 MiB
    unsigned short* attnb = (unsigned short*)(ws + ((size_t)136 << 20));// 32 MiB

    const int M = BB * SS;  // 16384

    cvt_f32_bf16<<<dim3((M * DD / 4 + 255) / 256), dim3(256), 0, stream>>>(
        (const float4*)x, (ushort4*)xb, M * DD / 4);
    transcvt<<<dim3(3 * DD / 32, DD / 32), dim3(256), 0, stream>>>(Wqkv, WqkvT, DD, 3 * DD);
    transcvt<<<dim3(DD / 32, DD / 32), dim3(256), 0, stream>>>(Wout, WoutT, DD, DD);

    // QKV = x @ Wqkv + bqkv  (bf16 out): grid 64 x 12 = 768 tiles
    gemm256<unsigned short><<<dim3((M / 256) * (3 * DD / 256)), dim3(512), 0, stream>>>(
        xb, WqkvT, bqkv, qkvb, M, 3 * DD, DD, 3 * DD / 256);

    col_attn_mfma<<<dim3(BB * BL), dim3(512), 0, stream>>>(qkvb, attnb);

    // out = attn @ Wout + bout  (fp32 out): grid 64 x 4 = 256 tiles
    gemm256<float><<<dim3((M / 256) * (DD / 256)), dim3(512), 0, stream>>>(
        attnb, WoutT, bout, out, M, DD, DD, DD / 256);
}

// Round 15
// 208.728 us; speedup vs baseline: 1.0239x; 1.0239x over previous
//
#include <hip/hip_runtime.h>
#include <math.h>

#define BB   4
#define SS   4096
#define DD   1024
#define BL   128
#define NB   32
#define PLANE 16777216   // 16384*1024 elems = one q'/k'/v' plane

typedef __attribute__((ext_vector_type(4))) float f32x4;
typedef __attribute__((ext_vector_type(16))) float f32x16;
typedef __attribute__((ext_vector_type(8))) short bf16x8;
typedef __attribute__((ext_vector_type(8))) unsigned short u16x8;

__device__ __forceinline__ float bf2f(unsigned short u) {
    return __uint_as_float(((unsigned int)u) << 16);
}
__device__ __forceinline__ unsigned short f2bf(float f) {
    unsigned int u = __float_as_uint(f);
    return (unsigned short)((u + 0x7FFFu + ((u >> 16) & 1u)) >> 16);  // RNE
}
__device__ __forceinline__ void gload_lds16(const unsigned short* g, unsigned short* l) {
    __builtin_amdgcn_global_load_lds(
        (const __attribute__((address_space(1))) void*)g,
        (__attribute__((address_space(3))) void*)l, 16, 0, 0);
}

// ---------------- fp32 -> bf16 elementwise ----------------
__global__ __launch_bounds__(256) void cvt_f32_bf16(const float4* __restrict__ in,
                                                    ushort4* __restrict__ out, int n4) {
    int i = blockIdx.x * 256 + threadIdx.x;
    if (i < n4) {
        float4 v = in[i];
        ushort4 o;
        o.x = f2bf(v.x); o.y = f2bf(v.y); o.z = f2bf(v.z); o.w = f2bf(v.w);
        out[i] = o;
    }
}

// ---------------- transpose + convert: W[K][N] f32 -> WT[N][K] bf16 ----------------
__global__ __launch_bounds__(256) void transcvt(const float* __restrict__ W,
                                                unsigned short* __restrict__ WT,
                                                int K, int N) {
    __shared__ float tile[32][33];
    const int n0 = blockIdx.x * 32, k0 = blockIdx.y * 32;
    const int tx = threadIdx.x & 31, ty = threadIdx.x >> 5;  // ty 0..7
    #pragma unroll
    for (int r = 0; r < 32; r += 8)
        tile[ty + r][tx] = W[(size_t)(k0 + ty + r) * N + n0 + tx];
    __syncthreads();
    #pragma unroll
    for (int r = 0; r < 32; r += 8)
        WT[(size_t)(n0 + ty + r) * K + k0 + tx] = f2bf(tile[tx][ty + r]);
}

// ---------------- 256x256 bf16 MFMA GEMM (r10/r13 schedule — frozen) ----------------
// Six schedule variants all pin at 113-116 us = ~903 TF (m97-structure ceiling).
// bf16-output path (QKV only) writes a PERMUTED layout: three planar regions
// q'/k'/v' (PLANE elems each) ordered (b, bl, nb, d) — row bit-swap
// [b:2][nb:5][bl:7] -> [b:2][bl:7][nb:5] — so the attention kernel's 32-row
// Q/K/V block reads become contiguous 64 KiB spans (stride 1024) instead of
// 12 KiB-strided scatter over 384 KiB. Write coalescing unchanged (contiguous
// 512 B runs per row). f32 path (out-GEMM) keeps the standard row-major layout.
// REGISTER BUDGET: 8 waves => 2 waves/SIMD => hard 256 regs/wave; acc=128 AGPR.

#define GBAR() __builtin_amdgcn_s_barrier()
#define LGKM(n) do { asm volatile("s_waitcnt lgkmcnt(" #n ")" ::: "memory"); \
                     __builtin_amdgcn_sched_barrier(0); } while (0)

#define MFMA_PAIR2(AR, q, ni) \
    acc[(q)*2+0][ni] = __builtin_amdgcn_mfma_f32_16x16x32_bf16(AR[0][0], bC[ni][0], acc[(q)*2+0][ni], 0, 0, 0); \
    acc[(q)*2+0][ni] = __builtin_amdgcn_mfma_f32_16x16x32_bf16(AR[0][1], bC[ni][1], acc[(q)*2+0][ni], 0, 0, 0); \
    acc[(q)*2+1][ni] = __builtin_amdgcn_mfma_f32_16x16x32_bf16(AR[1][0], bC[ni][0], acc[(q)*2+1][ni], 0, 0, 0); \
    acc[(q)*2+1][ni] = __builtin_amdgcn_mfma_f32_16x16x32_bf16(AR[1][1], bC[ni][1], acc[(q)*2+1][ni], 0, 0, 0);

#define MFMA_Q(AR, q) do { \
    __builtin_amdgcn_s_setprio(1); \
    MFMA_PAIR2(AR, q, 0) MFMA_PAIR2(AR, q, 1) \
    MFMA_PAIR2(AR, q, 2) MFMA_PAIR2(AR, q, 3) \
    __builtin_amdgcn_s_setprio(0); } while (0)

#define READ_AQ(dst, pA_, q) do { \
    dst[0][0] = *(const bf16x8*)((pA_) + ((q)*2+0)*1024 + sw0); \
    dst[0][1] = *(const bf16x8*)((pA_) + ((q)*2+0)*1024 + sw1); \
    dst[1][0] = *(const bf16x8*)((pA_) + ((q)*2+1)*1024 + sw0); \
    dst[1][1] = *(const bf16x8*)((pA_) + ((q)*2+1)*1024 + sw1); } while (0)

#define READ_B8(pB_) do { \
    bC[0][0] = *(const bf16x8*)((pB_) + 0*1024 + sw0); \
    bC[0][1] = *(const bf16x8*)((pB_) + 0*1024 + sw1); \
    bC[1][0] = *(const bf16x8*)((pB_) + 1*1024 + sw0); \
    bC[1][1] = *(const bf16x8*)((pB_) + 1*1024 + sw1); \
    bC[2][0] = *(const bf16x8*)((pB_) + 2*1024 + sw0); \
    bC[2][1] = *(const bf16x8*)((pB_) + 2*1024 + sw1); \
    bC[3][0] = *(const bf16x8*)((pB_) + 3*1024 + sw0); \
    bC[3][1] = *(const bf16x8*)((pB_) + 3*1024 + sw1); } while (0)

template<typename OutT>
__global__ __launch_bounds__(512, 1) void gemm256(
    const unsigned short* __restrict__ A, const unsigned short* __restrict__ BT,
    const float* __restrict__ bias, OutT* __restrict__ C,
    int M, int N, int K, int ntn)
{
    __shared__ __align__(16) unsigned short smem[65536];   // 128 KiB arena
    unsigned short* sAb = smem;
    unsigned short* sBb = smem + 32768;

    const int nwg = gridDim.x;
    const int wg  = blockIdx.x;
    const int swzb = (wg & 7) * (nwg >> 3) + (wg >> 3);   // bijective: nwg % 8 == 0
    const int m0 = (swzb / ntn) * 256, n0 = (swzb % ntn) * 256;

    const int t    = threadIdx.x;
    const int w    = t >> 6;
    const int lane = t & 63;
    const int wm   = w >> 2, wn = w & 3;

    const int srow8 = lane >> 3;
    const int sgch  = (lane & 7) ^ srow8;     // pre-swizzled global k-chunk
    const int NT    = K >> 6;                 // K-tiles of 64 (>= 2 for all launches)

    auto STAGE_A = [&](int ts, int cb) {
        const int r = cb + (w << 3);
        gload_lds16(A + (size_t)(m0 + r + srow8) * K + (ts << 6) + sgch * 8,
                    sAb + (size_t)(ts & 1) * 16384 + r * 64);
    };
    auto STAGE_B = [&](int ts, int cb) {
        const int r = cb + (w << 3);
        gload_lds16(BT + (size_t)(n0 + r + srow8) * K + (ts << 6) + sgch * 8,
                    sBb + (size_t)(ts & 1) * 16384 + r * 64);
    };

    const int frA = wm * 128 + (lane & 15);
    const int frB = wn * 64  + (lane & 15);
    const int sw0 = (((lane >> 4) + 0) ^ (lane & 7)) * 8;
    const int sw1 = (((lane >> 4) + 4) ^ (lane & 7)) * 8;

    f32x4 acc[8][4];
    #pragma unroll
    for (int i = 0; i < 8; ++i)
        #pragma unroll
        for (int j = 0; j < 4; ++j) acc[i][j] = (f32x4){0.f, 0.f, 0.f, 0.f};

    bf16x8 bC[4][2];               // single B-reg set (32 VGPRs)
    bf16x8 aX[2][2], aY[2][2];     // A-quarter ping-pong (16+16 VGPRs)

    // ---- prologue: tile0 full + B(1) + A(1)-half0; 6 loads stay in flight ----
    STAGE_B(0, 0); STAGE_B(0, 64); STAGE_B(0, 128); STAGE_B(0, 192);
    STAGE_A(0, 0); STAGE_A(0, 64); STAGE_A(0, 128); STAGE_A(0, 192);
    if (NT > 1) {
        STAGE_B(1, 0); STAGE_B(1, 64); STAGE_B(1, 128); STAGE_B(1, 192);
        STAGE_A(1, 0); STAGE_A(1, 128);
        asm volatile("s_waitcnt vmcnt(6)" ::: "memory");   // tile0 landed
    } else {
        asm volatile("s_waitcnt vmcnt(0)" ::: "memory");
    }
    GBAR();
    READ_AQ(aX, sAb + frA * 64, 0);   // A0(0); completion enforced by P1's LGKM(4)

    for (int ts = 0; ts < NT; ++ts) {
        const unsigned short* pAc = sAb + (size_t)(ts & 1) * 16384 + frA * 64;
        const unsigned short* pAn = sAb + (size_t)((ts + 1) & 1) * 16384 + frA * 64;
        const unsigned short* pBc = sBb + (size_t)(ts & 1) * 16384 + frB * 64;

        // ---- P1: read B(ts)+A1; stage A(ts+1)h1; wait (aX,B done); Q0 ----
        READ_B8(pBc);
        READ_AQ(aY, pAc, 1);
        if (ts + 1 < NT) { STAGE_A(ts + 1, 64); STAGE_A(ts + 1, 192); }
        LGKM(4); MFMA_Q(aX, 0); GBAR();

        // ---- P2: read A2; stage B(ts+2)-lo; wait A1; Q1 ----
        READ_AQ(aX, pAc, 2);
        if (ts + 2 < NT) { STAGE_B(ts + 2, 0); STAGE_B(ts + 2, 64); }
        LGKM(4); MFMA_Q(aY, 1); GBAR();

        // ---- P3: read A3; stage B(ts+2)-hi; wait A2; Q2 ----
        READ_AQ(aY, pAc, 3);
        if (ts + 2 < NT) { STAGE_B(ts + 2, 128); STAGE_B(ts + 2, 192); }
        LGKM(4); MFMA_Q(aX, 2); GBAR();

        // ---- P4: counted vmcnt -> read A0(ts+1); stage A(ts+2)h0; wait A3; Q3 ----
        if (ts + 1 < NT) {
            if (ts + 2 < NT) { asm volatile("s_waitcnt vmcnt(4)" ::: "memory"); }
            else             { asm volatile("s_waitcnt vmcnt(0)" ::: "memory"); }
            READ_AQ(aX, pAn, 0);
            if (ts + 2 < NT) { STAGE_A(ts + 2, 0); STAGE_A(ts + 2, 128); }
            LGKM(4); MFMA_Q(aY, 3);
        } else {
            LGKM(0); MFMA_Q(aY, 3);
        }
        GBAR();
    }

    // ---- epilogue: LDS-bounce for coalesced wide stores ----
    if constexpr (sizeof(OutT) == 2) {
        unsigned short (*cb)[256] = (unsigned short (*)[256])smem;
        #pragma unroll
        for (int ni = 0; ni < 4; ++ni) {
            const int col = wn * 64 + ni * 16 + (lane & 15);
            const float bv = bias[n0 + col];
            #pragma unroll
            for (int mi = 0; mi < 8; ++mi) {
                const int rb = wm * 128 + mi * 16 + ((lane >> 4) << 2);
                #pragma unroll
                for (int r = 0; r < 4; ++r)
                    cb[rb + r][col] = f2bf(acc[mi][ni][r] + bv);
            }
        }
        __syncthreads();
        // permuted planar store: region = gn>>10 (q/k/v), row [b|nb|bl] -> [b|bl|nb]
        unsigned short* Cp = (unsigned short*)C;
        #pragma unroll
        for (int it = 0; it < 16; ++it) {
            const int row = it * 16 + (t >> 5);
            const int cs  = (t & 31) * 8;
            const int gm  = m0 + row;
            const int gn  = n0 + cs;
            const int permrow = ((gm >> 12) << 12) | ((gm & 127) << 5) | ((gm >> 7) & 31);
            u16x8 v = *(const u16x8*)&cb[row][cs];
            *(u16x8*)(Cp + (size_t)(gn >> 10) * PLANE
                      + (size_t)permrow * 1024 + (gn & 1023)) = v;
        }
    } else {
        float (*cf)[256] = (float (*)[256])smem;
        #pragma unroll
        for (int h = 0; h < 2; ++h) {
            if (wm == h) {
                #pragma unroll
                for (int ni = 0; ni < 4; ++ni) {
                    const int col = wn * 64 + ni * 16 + (lane & 15);
                    const float bv = bias[n0 + col];
                    #pragma unroll
                    for (int mi = 0; mi < 8; ++mi) {
                        const int rb = mi * 16 + ((lane >> 4) << 2);  // 0..127
                        #pragma unroll
                        for (int r = 0; r < 4; ++r)
                            cf[rb + r][col] = acc[mi][ni][r] + bv;
                    }
                }
            }
            __syncthreads();
            float* Cp = (float*)C;
            #pragma unroll
            for (int it = 0; it < 16; ++it) {
                const int row = it * 8 + (t >> 6);     // 0..127
                const int c4  = (t & 63) * 4;
                float4 v = *(const float4*)&cf[row][c4];
                *(float4*)(Cp + (size_t)(m0 + h * 128 + row) * N + n0 + c4) = v;
            }
            __syncthreads();
        }
    }
}

// ---------------- column attention v4: planar (b,bl,nb,d) inputs, 8-wave ----------------
// One block per (b, bl), 512 threads (8 waves). Q/K/V now contiguous 64 KiB blocks
// (row stride 1024) from the GEMM's permuted epilogue — the MFMA fragment loads and
// PV row reads hit a tight footprint instead of 12 KiB-strided scatter.
__global__ __launch_bounds__(512) void col_attn_mfma(const unsigned short* __restrict__ qkv,
                                                     unsigned short* __restrict__ outb)
{
    const int b  = blockIdx.x >> 7;
    const int bl = blockIdx.x & (BL - 1);

    __shared__ float red[8][32][33];     // 33 KiB
    __shared__ float p_s[NB][NB + 1];

    const int t    = threadIdx.x;
    const int w    = t >> 6;
    const int lane = t & 63;

    const unsigned short* qb = qkv + (size_t)(b * BL + bl) * NB * 1024;  // 32 x 1024
    const unsigned short* kb = qb + PLANE;
    const unsigned short* vb = qb + 2 * (size_t)PLANE;

    // ---- QK^T: wave w covers k in [w*128, w*128+128), 8 MFMA steps ----
    {
        const int arow = lane & 31;
        const int khi  = (lane >> 5) * 8;
        const unsigned short* qp = qb + arow * 1024 + w * 128 + khi;
        const unsigned short* kp = qp + PLANE;

        f32x16 acc0 = {}, acc1 = {};
        #pragma unroll
        for (int s = 0; s < 8; s += 2) {
            bf16x8 aq0 = *(const bf16x8*)(qp + s * 16);
            bf16x8 bk0 = *(const bf16x8*)(kp + s * 16);
            bf16x8 aq1 = *(const bf16x8*)(qp + s * 16 + 16);
            bf16x8 bk1 = *(const bf16x8*)(kp + s * 16 + 16);
            acc0 = __builtin_amdgcn_mfma_f32_32x32x16_bf16(aq0, bk0, acc0, 0, 0, 0);
            acc1 = __builtin_amdgcn_mfma_f32_32x32x16_bf16(aq1, bk1, acc1, 0, 0, 0);
        }
        const int ccol = lane & 31;
        const int rhi  = (lane >> 5) * 4;
        #pragma unroll
        for (int r = 0; r < 16; ++r) {
            const int crow = (r & 3) + 8 * (r >> 2) + rhi;
            red[w][crow][ccol] = acc0[r] + acc1[r];
        }
    }
    __syncthreads();

    // ---- reduce 8 waves -> p_s, apply scale (512 threads: row=t>>4, 2 cols each) ----
    {
        const float scale = 1.0f / 32.0f;   // 1/sqrt(1024)
        const int row = t >> 4;
        const int c0  = (t & 15) * 2;
        #pragma unroll
        for (int j = 0; j < 2; ++j) {
            const int c = c0 + j;
            float s = red[0][row][c];
            #pragma unroll
            for (int ww = 1; ww < 8; ++ww) s += red[ww][row][c];
            p_s[row][c] = s * scale;
        }
    }
    __syncthreads();

    // ---- causal softmax (rows on lanes 0..31; tiny) ----
    if (t < NB) {
        const int i = t;
        float mx = p_s[i][0];
        for (int j = 1; j <= i; ++j) mx = fmaxf(mx, p_s[i][j]);
        float sum = 0.f;
        for (int j = 0; j <= i; ++j) { float e = __expf(p_s[i][j] - mx); p_s[i][j] = e; sum += e; }
        const float inv = 1.0f / sum;
        for (int j = 0; j <= i; ++j) p_s[i][j] *= inv;
        for (int j = i + 1; j < NB; ++j) p_s[i][j] = 0.f;
    }
    __syncthreads();

    // ---- PV: two 256-thread groups, balanced pass pairs {0,3} / {1,2} ----
    const int grp = t >> 8;              // 0 or 1
    const int tt  = t & 255;
    const int d0v = tt * 4;
    const int passes[2][2] = {{0, 3}, {1, 2}};
    #pragma unroll
    for (int pi = 0; pi < 2; ++pi) {
        const int p = passes[grp][pi];
        float4 accv[8];
        #pragma unroll
        for (int ii = 0; ii < 8; ++ii) accv[ii] = make_float4(0.f, 0.f, 0.f, 0.f);
        const int jmax = (p + 1) * 8;
        for (int j = 0; j < jmax; ++j) {
            ushort4 v4 = *(const ushort4*)(vb + j * 1024 + d0v);
            const float vx = bf2f(v4.x), vy = bf2f(v4.y), vz = bf2f(v4.z), vw = bf2f(v4.w);
            #pragma unroll
            for (int ii = 0; ii < 8; ++ii) {
                const float pij = p_s[p * 8 + ii][j];
                accv[ii].x += pij * vx;
                accv[ii].y += pij * vy;
                accv[ii].z += pij * vz;
                accv[ii].w += pij * vw;
            }
        }
        #pragma unroll
        for (int ii = 0; ii < 8; ++ii) {
            const int i = p * 8 + ii;
            ushort4 o;
            o.x = f2bf(accv[ii].x); o.y = f2bf(accv[ii].y);
            o.z = f2bf(accv[ii].z); o.w = f2bf(accv[ii].w);
            *(ushort4*)(outb + ((size_t)(b * NB + i) * BL + bl) * DD + d0v) = o;
        }
    }
}

extern "C" void kernel_launch(void* const* d_in, const int* in_sizes, int n_in,
                              void* d_out, int out_size, void* d_ws, size_t ws_size,
                              hipStream_t stream) {
    (void)in_sizes; (void)n_in; (void)out_size; (void)ws_size;
    const float* x    = (const float*)d_in[0];
    const float* Wqkv = (const float*)d_in[1];
    const float* bqkv = (const float*)d_in[2];
    const float* Wout = (const float*)d_in[3];
    const float* bout = (const float*)d_in[4];
    float* out = (float*)d_out;

    char* ws = (char*)d_ws;
    unsigned short* xb    = (unsigned short*)ws;                        // 32 MiB
    unsigned short* WqkvT = (unsigned short*)(ws + ((size_t)32 << 20)); //  6 MiB
    unsigned short* WoutT = (unsigned short*)(ws + ((size_t)38 << 20)); //  2 MiB
    unsigned short* qkvb  = (unsigned short*)(ws + ((size_t)40 << 20)); // 96 MiB (planar q'/k'/v')
    unsigned short* attnb = (unsigned short*)(ws + ((size_t)136 << 20));// 32 MiB

    const int M = BB * SS;  // 16384

    cvt_f32_bf16<<<dim3((M * DD / 4 + 255) / 256), dim3(256), 0, stream>>>(
        (const float4*)x, (ushort4*)xb, M * DD / 4);
    transcvt<<<dim3(3 * DD / 32, DD / 32), dim3(256), 0, stream>>>(Wqkv, WqkvT, DD, 3 * DD);
    transcvt<<<dim3(DD / 32, DD / 32), dim3(256), 0, stream>>>(Wout, WoutT, DD, DD);

    // QKV = x @ Wqkv + bqkv  (bf16, permuted planar out): grid 64 x 12 = 768 tiles
    gemm256<unsigned short><<<dim3((M / 256) * (3 * DD / 256)), dim3(512), 0, stream>>>(
        xb, WqkvT, bqkv, qkvb, M, 3 * DD, DD, 3 * DD / 256);

    col_attn_mfma<<<dim3(BB * BL), dim3(512), 0, stream>>>(qkvb, attnb);

    // out = attn @ Wout + bout  (fp32 out, standard layout): grid 64 x 4 = 256 tiles
    gemm256<float><<<dim3((M / 256) * (DD / 256)), dim3(512), 0, stream>>>(
        attnb, WoutT, bout, out, M, DD, DD, DD / 256);
}

// Round 16
// 205.203 us; speedup vs baseline: 1.0415x; 1.0172x over previous
//
#include <hip/hip_runtime.h>
#include <math.h>

#define BB   4
#define SS   4096
#define DD   1024
#define BL   128
#define NB   32
#define PLANE 16777216   // 16384*1024 elems = one q'/k'/v' plane

typedef __attribute__((ext_vector_type(4))) float f32x4;
typedef __attribute__((ext_vector_type(16))) float f32x16;
typedef __attribute__((ext_vector_type(8))) short bf16x8;
typedef __attribute__((ext_vector_type(8))) unsigned short u16x8;

__device__ __forceinline__ float bf2f(unsigned short u) {
    return __uint_as_float(((unsigned int)u) << 16);
}
__device__ __forceinline__ unsigned short f2bf(float f) {
    unsigned int u = __float_as_uint(f);
    return (unsigned short)((u + 0x7FFFu + ((u >> 16) & 1u)) >> 16);  // RNE
}
__device__ __forceinline__ void gload_lds16(const unsigned short* g, unsigned short* l) {
    __builtin_amdgcn_global_load_lds(
        (const __attribute__((address_space(1))) void*)g,
        (__attribute__((address_space(3))) void*)l, 16, 0, 0);
}

// ---------------- merged prep: x->bf16 + both W transposes, ONE dispatch ----------------
// blocks [0, 16384): cvt of x (4.19M float4); [16384, 19456): Wqkv^T; rest: Wout^T.
// Divergence is block-granular (zero lane cost); saves 2 launch gaps (~4-6 us).
__device__ __forceinline__ void transcvt_body(const float* __restrict__ W,
                                              unsigned short* __restrict__ WT,
                                              int K, int N, int n0, int k0,
                                              float (*tile)[33]) {
    const int tx = threadIdx.x & 31, ty = threadIdx.x >> 5;  // ty 0..7
    #pragma unroll
    for (int r = 0; r < 32; r += 8)
        tile[ty + r][tx] = W[(size_t)(k0 + ty + r) * N + n0 + tx];
    __syncthreads();
    #pragma unroll
    for (int r = 0; r < 32; r += 8)
        WT[(size_t)(n0 + ty + r) * K + k0 + tx] = f2bf(tile[tx][ty + r]);
}

__global__ __launch_bounds__(256) void prep(const float4* __restrict__ x4,
                                            ushort4* __restrict__ xb4, int n4,
                                            const float* __restrict__ Wqkv,
                                            unsigned short* __restrict__ WqkvT,
                                            const float* __restrict__ Wout,
                                            unsigned short* __restrict__ WoutT) {
    __shared__ float tile[32][33];
    const int bid = blockIdx.x;
    if (bid < 16384) {
        const int i = bid * 256 + threadIdx.x;
        if (i < n4) {
            float4 v = x4[i];
            ushort4 o;
            o.x = f2bf(v.x); o.y = f2bf(v.y); o.z = f2bf(v.z); o.w = f2bf(v.w);
            xb4[i] = o;
        }
    } else if (bid < 16384 + 3072) {
        const int idx = bid - 16384;                 // Wqkv: K=1024, N=3072
        transcvt_body(Wqkv, WqkvT, DD, 3 * DD, (idx % 96) * 32, (idx / 96) * 32, tile);
    } else {
        const int idx = bid - 16384 - 3072;          // Wout: K=1024, N=1024
        transcvt_body(Wout, WoutT, DD, DD, (idx % 32) * 32, (idx / 32) * 32, tile);
    }
}

// ---------------- 256x256 bf16 MFMA GEMM (r10/r13 schedule — frozen) ----------------
// Six schedule variants all pin at 113-116 us = ~903 TF (m97-structure ceiling).
// bf16-output path (QKV) writes the planar permuted (b,bl,nb,d) layout (r15, neutral
// but kept); f32 path (out-GEMM) standard row-major.
// REGISTER BUDGET: 8 waves => 2 waves/SIMD => hard 256 regs/wave; acc=128 AGPR.

#define GBAR() __builtin_amdgcn_s_barrier()
#define LGKM(n) do { asm volatile("s_waitcnt lgkmcnt(" #n ")" ::: "memory"); \
                     __builtin_amdgcn_sched_barrier(0); } while (0)

#define MFMA_PAIR2(AR, q, ni) \
    acc[(q)*2+0][ni] = __builtin_amdgcn_mfma_f32_16x16x32_bf16(AR[0][0], bC[ni][0], acc[(q)*2+0][ni], 0, 0, 0); \
    acc[(q)*2+0][ni] = __builtin_amdgcn_mfma_f32_16x16x32_bf16(AR[0][1], bC[ni][1], acc[(q)*2+0][ni], 0, 0, 0); \
    acc[(q)*2+1][ni] = __builtin_amdgcn_mfma_f32_16x16x32_bf16(AR[1][0], bC[ni][0], acc[(q)*2+1][ni], 0, 0, 0); \
    acc[(q)*2+1][ni] = __builtin_amdgcn_mfma_f32_16x16x32_bf16(AR[1][1], bC[ni][1], acc[(q)*2+1][ni], 0, 0, 0);

#define MFMA_Q(AR, q) do { \
    __builtin_amdgcn_s_setprio(1); \
    MFMA_PAIR2(AR, q, 0) MFMA_PAIR2(AR, q, 1) \
    MFMA_PAIR2(AR, q, 2) MFMA_PAIR2(AR, q, 3) \
    __builtin_amdgcn_s_setprio(0); } while (0)

#define READ_AQ(dst, pA_, q) do { \
    dst[0][0] = *(const bf16x8*)((pA_) + ((q)*2+0)*1024 + sw0); \
    dst[0][1] = *(const bf16x8*)((pA_) + ((q)*2+0)*1024 + sw1); \
    dst[1][0] = *(const bf16x8*)((pA_) + ((q)*2+1)*1024 + sw0); \
    dst[1][1] = *(const bf16x8*)((pA_) + ((q)*2+1)*1024 + sw1); } while (0)

#define READ_B8(pB_) do { \
    bC[0][0] = *(const bf16x8*)((pB_) + 0*1024 + sw0); \
    bC[0][1] = *(const bf16x8*)((pB_) + 0*1024 + sw1); \
    bC[1][0] = *(const bf16x8*)((pB_) + 1*1024 + sw0); \
    bC[1][1] = *(const bf16x8*)((pB_) + 1*1024 + sw1); \
    bC[2][0] = *(const bf16x8*)((pB_) + 2*1024 + sw0); \
    bC[2][1] = *(const bf16x8*)((pB_) + 2*1024 + sw1); \
    bC[3][0] = *(const bf16x8*)((pB_) + 3*1024 + sw0); \
    bC[3][1] = *(const bf16x8*)((pB_) + 3*1024 + sw1); } while (0)

template<typename OutT>
__global__ __launch_bounds__(512, 1) void gemm256(
    const unsigned short* __restrict__ A, const unsigned short* __restrict__ BT,
    const float* __restrict__ bias, OutT* __restrict__ C,
    int M, int N, int K, int ntn)
{
    __shared__ __align__(16) unsigned short smem[65536];   // 128 KiB arena
    unsigned short* sAb = smem;
    unsigned short* sBb = smem + 32768;

    const int nwg = gridDim.x;
    const int wg  = blockIdx.x;
    const int swzb = (wg & 7) * (nwg >> 3) + (wg >> 3);   // bijective: nwg % 8 == 0
    const int m0 = (swzb / ntn) * 256, n0 = (swzb % ntn) * 256;

    const int t    = threadIdx.x;
    const int w    = t >> 6;
    const int lane = t & 63;
    const int wm   = w >> 2, wn = w & 3;

    const int srow8 = lane >> 3;
    const int sgch  = (lane & 7) ^ srow8;     // pre-swizzled global k-chunk
    const int NT    = K >> 6;                 // K-tiles of 64 (>= 2 for all launches)

    auto STAGE_A = [&](int ts, int cb) {
        const int r = cb + (w << 3);
        gload_lds16(A + (size_t)(m0 + r + srow8) * K + (ts << 6) + sgch * 8,
                    sAb + (size_t)(ts & 1) * 16384 + r * 64);
    };
    auto STAGE_B = [&](int ts, int cb) {
        const int r = cb + (w << 3);
        gload_lds16(BT + (size_t)(n0 + r + srow8) * K + (ts << 6) + sgch * 8,
                    sBb + (size_t)(ts & 1) * 16384 + r * 64);
    };

    const int frA = wm * 128 + (lane & 15);
    const int frB = wn * 64  + (lane & 15);
    const int sw0 = (((lane >> 4) + 0) ^ (lane & 7)) * 8;
    const int sw1 = (((lane >> 4) + 4) ^ (lane & 7)) * 8;

    f32x4 acc[8][4];
    #pragma unroll
    for (int i = 0; i < 8; ++i)
        #pragma unroll
        for (int j = 0; j < 4; ++j) acc[i][j] = (f32x4){0.f, 0.f, 0.f, 0.f};

    bf16x8 bC[4][2];               // single B-reg set (32 VGPRs)
    bf16x8 aX[2][2], aY[2][2];     // A-quarter ping-pong (16+16 VGPRs)

    // ---- prologue: tile0 full + B(1) + A(1)-half0; 6 loads stay in flight ----
    STAGE_B(0, 0); STAGE_B(0, 64); STAGE_B(0, 128); STAGE_B(0, 192);
    STAGE_A(0, 0); STAGE_A(0, 64); STAGE_A(0, 128); STAGE_A(0, 192);
    if (NT > 1) {
        STAGE_B(1, 0); STAGE_B(1, 64); STAGE_B(1, 128); STAGE_B(1, 192);
        STAGE_A(1, 0); STAGE_A(1, 128);
        asm volatile("s_waitcnt vmcnt(6)" ::: "memory");   // tile0 landed
    } else {
        asm volatile("s_waitcnt vmcnt(0)" ::: "memory");
    }
    GBAR();
    READ_AQ(aX, sAb + frA * 64, 0);   // A0(0); completion enforced by P1's LGKM(4)

    for (int ts = 0; ts < NT; ++ts) {
        const unsigned short* pAc = sAb + (size_t)(ts & 1) * 16384 + frA * 64;
        const unsigned short* pAn = sAb + (size_t)((ts + 1) & 1) * 16384 + frA * 64;
        const unsigned short* pBc = sBb + (size_t)(ts & 1) * 16384 + frB * 64;

        // ---- P1: read B(ts)+A1; stage A(ts+1)h1; wait (aX,B done); Q0 ----
        READ_B8(pBc);
        READ_AQ(aY, pAc, 1);
        if (ts + 1 < NT) { STAGE_A(ts + 1, 64); STAGE_A(ts + 1, 192); }
        LGKM(4); MFMA_Q(aX, 0); GBAR();

        // ---- P2: read A2; stage B(ts+2)-lo; wait A1; Q1 ----
        READ_AQ(aX, pAc, 2);
        if (ts + 2 < NT) { STAGE_B(ts + 2, 0); STAGE_B(ts + 2, 64); }
        LGKM(4); MFMA_Q(aY, 1); GBAR();

        // ---- P3: read A3; stage B(ts+2)-hi; wait A2; Q2 ----
        READ_AQ(aY, pAc, 3);
        if (ts + 2 < NT) { STAGE_B(ts + 2, 128); STAGE_B(ts + 2, 192); }
        LGKM(4); MFMA_Q(aX, 2); GBAR();

        // ---- P4: counted vmcnt -> read A0(ts+1); stage A(ts+2)h0; wait A3; Q3 ----
        if (ts + 1 < NT) {
            if (ts + 2 < NT) { asm volatile("s_waitcnt vmcnt(4)" ::: "memory"); }
            else             { asm volatile("s_waitcnt vmcnt(0)" ::: "memory"); }
            READ_AQ(aX, pAn, 0);
            if (ts + 2 < NT) { STAGE_A(ts + 2, 0); STAGE_A(ts + 2, 128); }
            LGKM(4); MFMA_Q(aY, 3);
        } else {
            LGKM(0); MFMA_Q(aY, 3);
        }
        GBAR();
    }

    // ---- epilogue: LDS-bounce for coalesced wide stores ----
    if constexpr (sizeof(OutT) == 2) {
        unsigned short (*cb)[256] = (unsigned short (*)[256])smem;
        #pragma unroll
        for (int ni = 0; ni < 4; ++ni) {
            const int col = wn * 64 + ni * 16 + (lane & 15);
            const float bv = bias[n0 + col];
            #pragma unroll
            for (int mi = 0; mi < 8; ++mi) {
                const int rb = wm * 128 + mi * 16 + ((lane >> 4) << 2);
                #pragma unroll
                for (int r = 0; r < 4; ++r)
                    cb[rb + r][col] = f2bf(acc[mi][ni][r] + bv);
            }
        }
        __syncthreads();
        // permuted planar store: region = gn>>10 (q/k/v), row [b|nb|bl] -> [b|bl|nb]
        unsigned short* Cp = (unsigned short*)C;
        #pragma unroll
        for (int it = 0; it < 16; ++it) {
            const int row = it * 16 + (t >> 5);
            const int cs  = (t & 31) * 8;
            const int gm  = m0 + row;
            const int gn  = n0 + cs;
            const int permrow = ((gm >> 12) << 12) | ((gm & 127) << 5) | ((gm >> 7) & 31);
            u16x8 v = *(const u16x8*)&cb[row][cs];
            *(u16x8*)(Cp + (size_t)(gn >> 10) * PLANE
                      + (size_t)permrow * 1024 + (gn & 1023)) = v;
        }
    } else {
        float (*cf)[256] = (float (*)[256])smem;
        #pragma unroll
        for (int h = 0; h < 2; ++h) {
            if (wm == h) {
                #pragma unroll
                for (int ni = 0; ni < 4; ++ni) {
                    const int col = wn * 64 + ni * 16 + (lane & 15);
                    const float bv = bias[n0 + col];
                    #pragma unroll
                    for (int mi = 0; mi < 8; ++mi) {
                        const int rb = mi * 16 + ((lane >> 4) << 2);  // 0..127
                        #pragma unroll
                        for (int r = 0; r < 4; ++r)
                            cf[rb + r][col] = acc[mi][ni][r] + bv;
                    }
                }
            }
            __syncthreads();
            float* Cp = (float*)C;
            #pragma unroll
            for (int it = 0; it < 16; ++it) {
                const int row = it * 8 + (t >> 6);     // 0..127
                const int c4  = (t & 63) * 4;
                float4 v = *(const float4*)&cf[row][c4];
                *(float4*)(Cp + (size_t)(m0 + h * 128 + row) * N + n0 + c4) = v;
            }
            __syncthreads();
        }
    }
}

// ---------------- column attention v4: planar (b,bl,nb,d) inputs, 8-wave (frozen) ----------------
__global__ __launch_bounds__(512) void col_attn_mfma(const unsigned short* __restrict__ qkv,
                                                     unsigned short* __restrict__ outb)
{
    const int b  = blockIdx.x >> 7;
    const int bl = blockIdx.x & (BL - 1);

    __shared__ float red[8][32][33];     // 33 KiB
    __shared__ float p_s[NB][NB + 1];

    const int t    = threadIdx.x;
    const int w    = t >> 6;
    const int lane = t & 63;

    const unsigned short* qb = qkv + (size_t)(b * BL + bl) * NB * 1024;  // 32 x 1024
    const unsigned short* vb = qb + 2 * (size_t)PLANE;

    // ---- QK^T: wave w covers k in [w*128, w*128+128), 8 MFMA steps ----
    {
        const int arow = lane & 31;
        const int khi  = (lane >> 5) * 8;
        const unsigned short* qp = qb + arow * 1024 + w * 128 + khi;
        const unsigned short* kp = qp + PLANE;

        f32x16 acc0 = {}, acc1 = {};
        #pragma unroll
        for (int s = 0; s < 8; s += 2) {
            bf16x8 aq0 = *(const bf16x8*)(qp + s * 16);
            bf16x8 bk0 = *(const bf16x8*)(kp + s * 16);
            bf16x8 aq1 = *(const bf16x8*)(qp + s * 16 + 16);
            bf16x8 bk1 = *(const bf16x8*)(kp + s * 16 + 16);
            acc0 = __builtin_amdgcn_mfma_f32_32x32x16_bf16(aq0, bk0, acc0, 0, 0, 0);
            acc1 = __builtin_amdgcn_mfma_f32_32x32x16_bf16(aq1, bk1, acc1, 0, 0, 0);
        }
        const int ccol = lane & 31;
        const int rhi  = (lane >> 5) * 4;
        #pragma unroll
        for (int r = 0; r < 16; ++r) {
            const int crow = (r & 3) + 8 * (r >> 2) + rhi;
            red[w][crow][ccol] = acc0[r] + acc1[r];
        }
    }
    __syncthreads();

    // ---- reduce 8 waves -> p_s, apply scale (512 threads: row=t>>4, 2 cols each) ----
    {
        const float scale = 1.0f / 32.0f;   // 1/sqrt(1024)
        const int row = t >> 4;
        const int c0  = (t & 15) * 2;
        #pragma unroll
        for (int j = 0; j < 2; ++j) {
            const int c = c0 + j;
            float s = red[0][row][c];
            #pragma unroll
            for (int ww = 1; ww < 8; ++ww) s += red[ww][row][c];
            p_s[row][c] = s * scale;
        }
    }
    __syncthreads();

    // ---- causal softmax (rows on lanes 0..31; tiny) ----
    if (t < NB) {
        const int i = t;
        float mx = p_s[i][0];
        for (int j = 1; j <= i; ++j) mx = fmaxf(mx, p_s[i][j]);
        float sum = 0.f;
        for (int j = 0; j <= i; ++j) { float e = __expf(p_s[i][j] - mx); p_s[i][j] = e; sum += e; }
        const float inv = 1.0f / sum;
        for (int j = 0; j <= i; ++j) p_s[i][j] *= inv;
        for (int j = i + 1; j < NB; ++j) p_s[i][j] = 0.f;
    }
    __syncthreads();

    // ---- PV: two 256-thread groups, balanced pass pairs {0,3} / {1,2} ----
    const int grp = t >> 8;              // 0 or 1
    const int tt  = t & 255;
    const int d0v = tt * 4;
    const int passes[2][2] = {{0, 3}, {1, 2}};
    #pragma unroll
    for (int pi = 0; pi < 2; ++pi) {
        const int p = passes[grp][pi];
        float4 accv[8];
        #pragma unroll
        for (int ii = 0; ii < 8; ++ii) accv[ii] = make_float4(0.f, 0.f, 0.f, 0.f);
        const int jmax = (p + 1) * 8;
        for (int j = 0; j < jmax; ++j) {
            ushort4 v4 = *(const ushort4*)(vb + j * 1024 + d0v);
            const float vx = bf2f(v4.x), vy = bf2f(v4.y), vz = bf2f(v4.z), vw = bf2f(v4.w);
            #pragma unroll
            for (int ii = 0; ii < 8; ++ii) {
                const float pij = p_s[p * 8 + ii][j];
                accv[ii].x += pij * vx;
                accv[ii].y += pij * vy;
                accv[ii].z += pij * vz;
                accv[ii].w += pij * vw;
            }
        }
        #pragma unroll
        for (int ii = 0; ii < 8; ++ii) {
            const int i = p * 8 + ii;
            ushort4 o;
            o.x = f2bf(accv[ii].x); o.y = f2bf(accv[ii].y);
            o.z = f2bf(accv[ii].z); o.w = f2bf(accv[ii].w);
            *(ushort4*)(outb + ((size_t)(b * NB + i) * BL + bl) * DD + d0v) = o;
        }
    }
}

extern "C" void kernel_launch(void* const* d_in, const int* in_sizes, int n_in,
                              void* d_out, int out_size, void* d_ws, size_t ws_size,
                              hipStream_t stream) {
    (void)in_sizes; (void)n_in; (void)out_size; (void)ws_size;
    const float* x    = (const float*)d_in[0];
    const float* Wqkv = (const float*)d_in[1];
    const float* bqkv = (const float*)d_in[2];
    const float* Wout = (const float*)d_in[3];
    const float* bout = (const float*)d_in[4];
    float* out = (float*)d_out;

    char* ws = (char*)d_ws;
    unsigned short* xb    = (unsigned short*)ws;                        // 32 MiB
    unsigned short* WqkvT = (unsigned short*)(ws + ((size_t)32 << 20)); //  6 MiB
    unsigned short* WoutT = (unsigned short*)(ws + ((size_t)38 << 20)); //  2 MiB
    unsigned short* qkvb  = (unsigned short*)(ws + ((size_t)40 << 20)); // 96 MiB (planar q'/k'/v')
    unsigned short* attnb = (unsigned short*)(ws + ((size_t)136 << 20));// 32 MiB

    const int M = BB * SS;  // 16384
    const int n4 = M * DD / 4;  // 4194304

    // merged prep: cvt (16384 blocks) + WqkvT (3072) + WoutT (1024)
    prep<<<dim3(16384 + 3072 + 1024), dim3(256), 0, stream>>>(
        (const float4*)x, (ushort4*)xb, n4, Wqkv, WqkvT, Wout, WoutT);

    // QKV = x @ Wqkv + bqkv  (bf16, permuted planar out): grid 64 x 12 = 768 tiles
    gemm256<unsigned short><<<dim3((M / 256) * (3 * DD / 256)), dim3(512), 0, stream>>>(
        xb, WqkvT, bqkv, qkvb, M, 3 * DD, DD, 3 * DD / 256);

    col_attn_mfma<<<dim3(BB * BL), dim3(512), 0, stream>>>(qkvb, attnb);

    // out = attn @ Wout + bout  (fp32 out, standard layout): grid 64 x 4 = 256 tiles
    gemm256<float><<<dim3((M / 256) * (DD / 256)), dim3(512), 0, stream>>>(
        attnb, WoutT, bout, out, M, DD, DD, DD / 256);
}